// Round 1
// baseline (473.667 us; speedup 1.0000x reference)
//
#include <hip/hip_runtime.h>

#define TT 2048

// tanh(y) where z = 2*log2(e)*y has been pre-folded into the weights:
// tanh(y) = 1 - 2/(1 + exp2(z))
__device__ __forceinline__ float tanh_pre(float z) {
    float t = __builtin_amdgcn_exp2f(z);
    float r = __builtin_amdgcn_rcpf(1.0f + t);
    return fmaf(-2.0f, r, 1.0f);
}

__global__ __launch_bounds__(64, 1)
void stn_seq_kernel(const float* __restrict__ x,
                    const float* __restrict__ W1,
                    const float* __restrict__ W2,
                    const float* __restrict__ b2,
                    const float* __restrict__ W3,
                    const float* __restrict__ W4,
                    float* __restrict__ out, int B)
{
    const int b = blockIdx.x * blockDim.x + threadIdx.x;
    if (b >= B) return;
    const float K = 2.8853900817779268f; // 2*log2(e)

    // Load tiny weights once (uniform -> scalar loads), pre-scale by K so the
    // matvec FMA output is directly the exp2 argument.
    float w1x[4], w1s[4], w2[4][4], bb[4], w3[4][4], w4[4];
    #pragma unroll
    for (int i = 0; i < 4; ++i) {
        w1x[i] = W1[i*2+0] * K;
        w1s[i] = W1[i*2+1] * K;
        bb[i]  = b2[i] * K;
        w4[i]  = W4[i];
        #pragma unroll
        for (int j = 0; j < 4; ++j) {
            w2[i][j] = W2[i*4+j] * K;
            w3[i][j] = W3[i*4+j] * K;
        }
    }

    const float* xp = x + b;
    float* op = out + b;
    float s = 0.0f;

    constexpr int U = 4;          // prefetch depth / unroll
    float xb[U];
    #pragma unroll
    for (int k = 0; k < U; ++k) xb[k] = __builtin_nontemporal_load(xp + k*B);
    xp += (size_t)U * B;

    for (int t = 0; t < TT; t += U) {
        float xc[U];
        #pragma unroll
        for (int k = 0; k < U; ++k) xc[k] = xb[k];
        if (t + U < TT) {
            #pragma unroll
            for (int k = 0; k < U; ++k) xb[k] = __builtin_nontemporal_load(xp + k*B);
        }
        xp += (size_t)U * B;

        #pragma unroll
        for (int k = 0; k < U; ++k) {
            float h1[4], h2[4], h3[4];
            #pragma unroll
            for (int i = 0; i < 4; ++i)
                h1[i] = tanh_pre(fmaf(w1s[i], s, w1x[i] * xc[k]));
            #pragma unroll
            for (int i = 0; i < 4; ++i) {
                float a = bb[i];
                #pragma unroll
                for (int j = 0; j < 4; ++j) a = fmaf(w2[i][j], h1[j], a);
                h2[i] = tanh_pre(a);
            }
            #pragma unroll
            for (int i = 0; i < 4; ++i) {
                float a = w3[i][0] * h2[0];
                #pragma unroll
                for (int j = 1; j < 4; ++j) a = fmaf(w3[i][j], h2[j], a);
                h3[i] = tanh_pre(a);
            }
            float d = w4[0] * h3[0];
            d = fmaf(w4[1], h3[1], d);
            d = fmaf(w4[2], h3[2], d);
            d = fmaf(w4[3], h3[3], d);
            s += d;
            __builtin_nontemporal_store(s, op);
            op += B;
        }
    }
}

extern "C" void kernel_launch(void* const* d_in, const int* in_sizes, int n_in,
                              void* d_out, int out_size, void* d_ws, size_t ws_size,
                              hipStream_t stream)
{
    const float* x  = (const float*)d_in[0];
    const float* W1 = (const float*)d_in[1];
    // robust to W2/b2 ordering ambiguity: identify by element counts
    const float* A2 = (const float*)d_in[2];
    const float* A3 = (const float*)d_in[3];
    const float* W3 = (const float*)d_in[4];
    const float* W4 = (const float*)d_in[5];
    const float* W2 = (in_sizes[2] == 16) ? A2 : A3;
    const float* b2 = (in_sizes[2] == 16) ? A3 : A2;

    const int B = in_sizes[0] / TT;
    float* out = (float*)d_out;

    dim3 block(64);
    dim3 grid((B + 63) / 64);
    hipLaunchKernelGGL(stn_seq_kernel, grid, block, 0, stream,
                       x, W1, W2, b2, W3, W4, out, B);
}

// Round 2
// 429.113 us; speedup vs baseline: 1.1038x; 1.1038x over previous
//
#include <hip/hip_runtime.h>

#define TT 2048

// tanh(y) where z = 2*log2(e)*y has been pre-folded into the weights:
// tanh(y) = 1 - 2/(1 + exp2(z))
__device__ __forceinline__ float tanh_pre(float z) {
    float t = __builtin_amdgcn_exp2f(z);
    float r = __builtin_amdgcn_rcpf(1.0f + t);
    return fmaf(-2.0f, r, 1.0f);
}

// DPP quad_perm cross-lane move (VALU pipe, all lanes active)
template<int CTRL>
__device__ __forceinline__ float dpp_f(float x) {
    return __int_as_float(__builtin_amdgcn_mov_dpp(__float_as_int(x), CTRL, 0xf, 0xf, true));
}
// quad_perm[a,b,c,d] = a | b<<2 | c<<4 | d<<6 ; lane i reads lane "slot i"
#define QP_ROT1 0x39  // [1,2,3,0]: lane i <- lane (i+1)&3
#define QP_ROT2 0x4E  // [2,3,0,1]: lane i <- lane (i+2)&3
#define QP_ROT3 0x93  // [3,0,1,2]: lane i <- lane (i+3)&3
#define QP_XOR1 0xB1  // [1,0,3,2]: lane i <- lane i^1

__global__ __launch_bounds__(256, 1)
void stn_quad_kernel(const float* __restrict__ x,
                     const float* __restrict__ W1,
                     const float* __restrict__ W2,
                     const float* __restrict__ b2,
                     const float* __restrict__ W3,
                     const float* __restrict__ W4,
                     float* __restrict__ out, int B)
{
    const int tid = blockIdx.x * blockDim.x + threadIdx.x;
    const int q   = tid & 3;      // hidden-unit index owned by this lane
    const int b   = tid >> 2;     // sequence index (one per 4-lane quad)
    if (b >= B) return;
    const float K = 2.8853900817779268f; // 2*log2(e)

    // Per-lane weights: lane q owns row q of each layer. Rotation-aligned
    // gathers so that a_q = sum_r w[q][(q+r)&3] * rot_r(h).
    const float w1x = W1[q*2+0] * K;
    const float w1s = W1[q*2+1] * K;
    const float bb  = b2[q] * K;
    const float w4l = W4[q];
    float w2q[4], w3q[4];
    #pragma unroll
    for (int r = 0; r < 4; ++r) {
        w2q[r] = W2[q*4 + ((q+r)&3)] * K;
        w3q[r] = W3[q*4 + ((q+r)&3)] * K;
    }

    const float* xp = x + b;
    float* op = out + b;
    float s = 0.0f;

    constexpr int U = 4;          // x prefetch depth
    float xb[U];
    #pragma unroll
    for (int k = 0; k < U; ++k) xb[k] = __builtin_nontemporal_load(xp + k*B);
    xp += (size_t)U * B;

    for (int t = 0; t < TT; t += U) {
        float xc[U];
        #pragma unroll
        for (int k = 0; k < U; ++k) xc[k] = xb[k];
        if (t + U < TT) {
            #pragma unroll
            for (int k = 0; k < U; ++k) xb[k] = __builtin_nontemporal_load(xp + k*B);
        }
        xp += (size_t)U * B;

        #pragma unroll
        for (int k = 0; k < U; ++k) {
            // layer 1: h1_q = tanh(W1[q,0]*x + W1[q,1]*s)
            float h1 = tanh_pre(fmaf(w1s, s, w1x * xc[k]));

            // layer 2: gather quad h1 via DPP rotations
            float h1r1 = dpp_f<QP_ROT1>(h1);
            float h1r2 = dpp_f<QP_ROT2>(h1);
            float h1r3 = dpp_f<QP_ROT3>(h1);
            float a2 = bb;
            a2 = fmaf(w2q[0], h1,   a2);
            a2 = fmaf(w2q[1], h1r1, a2);
            a2 = fmaf(w2q[2], h1r2, a2);
            a2 = fmaf(w2q[3], h1r3, a2);
            float h2 = tanh_pre(a2);

            // layer 3
            float h2r1 = dpp_f<QP_ROT1>(h2);
            float h2r2 = dpp_f<QP_ROT2>(h2);
            float h2r3 = dpp_f<QP_ROT3>(h2);
            float a3 = w3q[0] * h2;
            a3 = fmaf(w3q[1], h2r1, a3);
            a3 = fmaf(w3q[2], h2r2, a3);
            a3 = fmaf(w3q[3], h2r3, a3);
            float h3 = tanh_pre(a3);

            // layer 4 + residual: d = sum_q w4[q]*h3_q via quad butterfly
            float p = w4l * h3;
            p += dpp_f<QP_XOR1>(p);
            p += dpp_f<QP_ROT2>(p);   // rot2 == xor2 within a quad
            s += p;                   // every lane keeps the state copy

            if (q == 0) __builtin_nontemporal_store(s, op);
            op += B;
        }
    }
}

extern "C" void kernel_launch(void* const* d_in, const int* in_sizes, int n_in,
                              void* d_out, int out_size, void* d_ws, size_t ws_size,
                              hipStream_t stream)
{
    const float* x  = (const float*)d_in[0];
    const float* W1 = (const float*)d_in[1];
    // robust to W2/b2 ordering ambiguity: identify by element counts
    const float* A2 = (const float*)d_in[2];
    const float* A3 = (const float*)d_in[3];
    const float* W3 = (const float*)d_in[4];
    const float* W4 = (const float*)d_in[5];
    const float* W2 = (in_sizes[2] == 16) ? A2 : A3;
    const float* b2 = (in_sizes[2] == 16) ? A3 : A2;

    const int B = in_sizes[0] / TT;
    float* out = (float*)d_out;

    const int threads = B * 4;
    dim3 block(256);
    dim3 grid((threads + 255) / 256);
    hipLaunchKernelGGL(stn_quad_kernel, grid, block, 0, stream,
                       x, W1, W2, b2, W3, W4, out, B);
}

// Round 3
// 389.647 us; speedup vs baseline: 1.2156x; 1.1013x over previous
//
#include <hip/hip_runtime.h>

#define TT 2048

// DPP quad_perm cross-lane move (VALU pipe)
template<int CTRL>
__device__ __forceinline__ float dpp_f(float x) {
    return __int_as_float(__builtin_amdgcn_mov_dpp(__float_as_int(x), CTRL, 0xf, 0xf, true));
}
#define QP_ROT1 0x39  // lane i <- lane (i+1)&3
#define QP_ROT2 0x4E  // lane i <- lane (i+2)&3
#define QP_ROT3 0x93  // lane i <- lane (i+3)&3

// r = 1/(1+exp2(z));  tanh(y) = 1 - 2r with z = 2*log2(e)*y (folded into weights)
__device__ __forceinline__ float sigma_r(float z) {
    return __builtin_amdgcn_rcpf(1.0f + __builtin_amdgcn_exp2f(z));
}

__global__ __launch_bounds__(512, 2)
void stn_oct_kernel(const float* __restrict__ x,
                    const float* __restrict__ W1,
                    const float* __restrict__ W2,
                    const float* __restrict__ b2,
                    const float* __restrict__ W3,
                    const float* __restrict__ W4,
                    float* __restrict__ out, int B)
{
    const int tid = blockIdx.x * blockDim.x + threadIdx.x;
    const int o   = tid & 7;   // octet lane: two quads duplicate work; o also = store row
    const int q   = o & 3;     // hidden-unit index
    const int b   = tid >> 3;  // sequence index
    if (b >= B) return;
    const float K = 2.8853900817779268f; // 2*log2(e)

    // Folded weights: every layer consumes r (=sigmoid) directly.
    // z_layer = B' + sum_j A'_j * r_j, A' = -2K*W, B' = K*(bias + sum_j W_j)
    const float Kw1x = W1[2*q]   * K;
    const float Kw1s = W1[2*q+1] * K;
    float B2 = b2[q], B3 = 0.f, C4 = 0.f;
    float a2[4], a3[4], a4[4];
    #pragma unroll
    for (int r = 0; r < 4; ++r) {
        const int j = (q + r) & 3;           // rotation-aligned gather
        a2[r] = -2.f * K * W2[q*4 + j];
        a3[r] = -2.f * K * W3[q*4 + j];
        a4[r] = -2.f * W4[j];
        B2 += W2[q*4 + r];
        B3 += W3[q*4 + r];
        C4 += W4[r];
    }
    B2 *= K; B3 *= K;

    const float* xp = x + b;
    float* op = out + b + (size_t)o * B;

    float cur[8], nxt[8];
    #pragma unroll
    for (int j = 0; j < 8; ++j) cur[j] = __builtin_nontemporal_load(xp + j*B);
    #pragma unroll
    for (int j = 0; j < 8; ++j) nxt[j] = __builtin_nontemporal_load(xp + (8+j)*B);

    // State: psum = sum_j A4_j*r3_j from previous step (0 initially),
    // sC = s_t + C4, pre2 = Kw1x*x_t + Kw1s*(s_{t-1}+C4) so that
    // z1(t) = pre2 + Kw1s*psum.  s_0 = 0.
    float psum = 0.f;
    float sC   = C4;
    float pre2 = Kw1x * cur[0];

    for (int t = 0; t < TT; t += 8) {
        float outv[8];
        #pragma unroll
        for (int k = 0; k < 8; ++k) {
            // ---- critical chain head: layer 1 ----
            float z1 = fmaf(Kw1s, psum, pre2);
            float r1 = sigma_r(z1);
            // off-chain: prepare pre2 for next step (uses OLD sC = s_t + C4)
            float xn = (k < 7) ? cur[k+1] : nxt[0];
            pre2 = fmaf(Kw1s, sC, Kw1x * xn);
            // ---- layer 2 ----
            float rA = dpp_f<QP_ROT1>(r1);
            float rB = dpp_f<QP_ROT2>(r1);
            float rC = dpp_f<QP_ROT3>(r1);
            float m0 = fmaf(a2[0], r1, B2);
            float u1 = fmaf(a2[1], rA, m0);
            float v  = a2[2] * rB;
            float u2 = fmaf(a2[3], rC, v);
            float r2 = sigma_r(u1 + u2);
            // ---- layer 3 ----
            rA = dpp_f<QP_ROT1>(r2);
            rB = dpp_f<QP_ROT2>(r2);
            rC = dpp_f<QP_ROT3>(r2);
            m0 = fmaf(a3[0], r2, B3);
            u1 = fmaf(a3[1], rA, m0);
            v  = a3[2] * rB;
            u2 = fmaf(a3[3], rC, v);
            float r3 = sigma_r(u1 + u2);
            // ---- layer 4 quad-reduce (3-dpp tree, all lanes get sum) ----
            rA = dpp_f<QP_ROT1>(r3);
            rB = dpp_f<QP_ROT2>(r3);
            rC = dpp_f<QP_ROT3>(r3);
            float p0 = a4[0] * r3;
            u1 = fmaf(a4[1], rA, p0);
            v  = a4[2] * rB;
            u2 = fmaf(a4[3], rC, v);
            psum = u1 + u2;
            // off-chain: state & output
            outv[k] = sC + psum;      // = s_{t+1} (stored value)
            sC = outv[k] + C4;
        }
        // full-wave batched store: lane o stores step t+o
        float s01 = (o & 1) ? outv[1] : outv[0];
        float s23 = (o & 1) ? outv[3] : outv[2];
        float s45 = (o & 1) ? outv[5] : outv[4];
        float s67 = (o & 1) ? outv[7] : outv[6];
        float sA  = (o & 2) ? s23 : s01;
        float sB  = (o & 2) ? s67 : s45;
        float sv  = (o & 4) ? sB  : sA;
        __builtin_nontemporal_store(sv, op);
        op += (size_t)8 * B;
        // rotate x buffers, prefetch block t+16
        #pragma unroll
        for (int j = 0; j < 8; ++j) cur[j] = nxt[j];
        if (t + 16 < TT) {
            #pragma unroll
            for (int j = 0; j < 8; ++j)
                nxt[j] = __builtin_nontemporal_load(xp + (size_t)(t+16+j)*B);
        }
    }
}

extern "C" void kernel_launch(void* const* d_in, const int* in_sizes, int n_in,
                              void* d_out, int out_size, void* d_ws, size_t ws_size,
                              hipStream_t stream)
{
    const float* x  = (const float*)d_in[0];
    const float* W1 = (const float*)d_in[1];
    const float* A2 = (const float*)d_in[2];
    const float* A3 = (const float*)d_in[3];
    const float* W3 = (const float*)d_in[4];
    const float* W4 = (const float*)d_in[5];
    const float* W2 = (in_sizes[2] == 16) ? A2 : A3;
    const float* b2 = (in_sizes[2] == 16) ? A3 : A2;

    const int B = in_sizes[0] / TT;
    float* out = (float*)d_out;

    const int threads = B * 8;
    dim3 block(512);
    dim3 grid((threads + 511) / 512);
    hipLaunchKernelGGL(stn_oct_kernel, grid, block, 0, stream,
                       x, W1, W2, b2, W3, W4, out, B);
}